// Round 6
// baseline (116.104 us; speedup 1.0000x reference)
//
#include <hip/hip_runtime.h>
#include <math.h>

#define N_B 2
#define HH 48
#define WW 48
#define DM 256
#define NH 4
#define EH 64
#define KS 7
#define NPIX (N_B*HH*WW)    // 4608

typedef _Float16 half8 __attribute__((ext_vector_type(8)));
typedef float float4v __attribute__((ext_vector_type(4)));

// ---------------- scale = cond @ w_norm.T + 1 ----------------
__global__ void scale_kernel(const float* __restrict__ cond,
                             const float* __restrict__ w_norm,
                             float* __restrict__ scale) {
    int b = blockIdx.x;
    int t = threadIdx.x, wave = t >> 6, lane = t & 63;
    int d = blockIdx.y*32 + wave*8 + (lane >> 3);
    int l8 = lane & 7;
    const float4* wr4 = (const float4*)(w_norm + (size_t)d*DM) + l8*8;
    const float4* c4  = (const float4*)(cond + (size_t)b*DM) + l8*8;
    float acc = 0.f;
    #pragma unroll
    for (int j = 0; j < 8; ++j) {
        float4 w = wr4[j], c = c4[j];
        acc += w.x*c.x + w.y*c.y + w.z*c.z + w.w*c.w;
    }
    acc += __shfl_xor(acc, 1, 64);
    acc += __shfl_xor(acc, 2, 64);
    acc += __shfl_xor(acc, 4, 64);
    if (l8 == 0) scale[b*DM + d] = acc + 1.0f;
}

// ---------------- fused RMSNorm + QKV GEMM + RoPE ----------------
// Block = 64 pixels x 64 outputs (one sel,head). Whole K=256 staged in LDS once; barrier-free k-loop.
__global__ __launch_bounds__(256) void fused_qkv(const float* __restrict__ x,
                                                 const float* __restrict__ scale,
                                                 const float* __restrict__ B,
                                                 const float* __restrict__ pos,
                                                 _Float16* __restrict__ qh,
                                                 _Float16* __restrict__ kh,
                                                 _Float16* __restrict__ vh) {
    const int K = DM, LDA = 264;            // 528B row stride: 16B-aligned, 4-banks/row advance
    __shared__ _Float16 As[64*LDA];
    __shared__ _Float16 Bs[64*LDA];
    __shared__ float scale_sh[DM];
    int t = threadIdx.x;
    int wave = t >> 6, lane = t & 63;
    int m0 = blockIdx.x*64, n0 = blockIdx.y*64;
    int b = m0 / (HH*WW);                   // 64-pixel tiles never straddle batches (2304 % 64 == 0)

    scale_sh[t] = scale[b*DM + t];

    // RMS of this thread's row-quarter: thread (row=t>>2, seg=t&3) owns x[m0+row][seg*64..+64)
    int row = t >> 2, seg = t & 3;
    const float4* xp = (const float4*)(x + (size_t)(m0+row)*DM + seg*64);
    float4 xr[16];
    float ss = 0.f;
    #pragma unroll
    for (int j = 0; j < 16; ++j) {
        xr[j] = xp[j];
        ss += xr[j].x*xr[j].x + xr[j].y*xr[j].y + xr[j].z*xr[j].z + xr[j].w*xr[j].w;
    }
    ss += __shfl_xor(ss, 1, 64);            // 4 seg-threads are adjacent lanes
    ss += __shfl_xor(ss, 2, 64);
    float rms = rsqrtf(ss*(1.0f/DM) + 1e-6f);
    __syncthreads();                        // scale_sh ready

    // write normalized fp16 A-tile
    #pragma unroll
    for (int j = 0; j < 8; ++j) {
        int ch = seg*64 + j*8;
        float4 a = xr[2*j], c = xr[2*j+1];
        half8 hv;
        hv[0]=(_Float16)(a.x*scale_sh[ch+0]*rms); hv[1]=(_Float16)(a.y*scale_sh[ch+1]*rms);
        hv[2]=(_Float16)(a.z*scale_sh[ch+2]*rms); hv[3]=(_Float16)(a.w*scale_sh[ch+3]*rms);
        hv[4]=(_Float16)(c.x*scale_sh[ch+4]*rms); hv[5]=(_Float16)(c.y*scale_sh[ch+5]*rms);
        hv[6]=(_Float16)(c.z*scale_sh[ch+6]*rms); hv[7]=(_Float16)(c.w*scale_sh[ch+7]*rms);
        *(half8*)&As[row*LDA + ch] = hv;
    }
    // stage full B tile (fp32 -> fp16)
    {
        const float4* bp = (const float4*)(B + (size_t)(n0+row)*K + seg*64);
        #pragma unroll
        for (int j = 0; j < 8; ++j) {
            float4 b0 = bp[2*j], b1 = bp[2*j+1];
            half8 hb;
            hb[0]=(_Float16)b0.x; hb[1]=(_Float16)b0.y; hb[2]=(_Float16)b0.z; hb[3]=(_Float16)b0.w;
            hb[4]=(_Float16)b1.x; hb[5]=(_Float16)b1.y; hb[6]=(_Float16)b1.z; hb[7]=(_Float16)b1.w;
            *(half8*)&Bs[row*LDA + seg*64 + j*8] = hb;
        }
    }
    __syncthreads();

    // barrier-free k-loop over the fully-staged tiles
    int frow = lane & 15, kq = (lane >> 4) * 8;
    float4v acc[4];
    #pragma unroll
    for (int ni = 0; ni < 4; ++ni) acc[ni] = (float4v){0.f,0.f,0.f,0.f};
    #pragma unroll
    for (int ks = 0; ks < 8; ++ks) {
        int k0 = ks*32;
        half8 af = *(const half8*)&As[(wave*16 + frow)*LDA + k0 + kq];
        #pragma unroll
        for (int ni = 0; ni < 4; ++ni) {
            half8 bf = *(const half8*)&Bs[(ni*16 + frow)*LDA + k0 + kq];
            acc[ni] = __builtin_amdgcn_mfma_f32_16x16x32_f16(af, bf, acc[ni], 0, 0, 0);
        }
    }

    // Epilogue: e = ni*16 + col; rope pairs (e, e+16) = (ni=0, ni=1), same lane.
    int sel  = n0 >> 8;
    int head = (n0 >> 6) & 3;
    _Float16* outp = (sel == 0) ? qh : (sel == 1) ? kh : vh;
    int col = lane & 15, rbase = (lane >> 4) * 4;
    float freq = __expf(1.14472988585f + (float)(col & 7) * 0.287823136624f); // pi * 10^(mf/8)
    #pragma unroll
    for (int r = 0; r < 4; ++r) {
        int pix = m0 + wave*16 + rbase + r;
        float v0 = acc[0][r], v1 = acc[1][r], v2 = acc[2][r], v3 = acc[3][r];
        if (sel < 2) {
            int hw = pix % (HH*WW);
            float p = (col < 8) ? pos[hw*2] : pos[hw*2+1];
            float sn, cs;
            __sincosf(p*freq, &sn, &cs);
            float o0 = v0*cs - v1*sn;
            float o1 = v1*cs + v0*sn;
            v0 = o0; v1 = o1;
            if (sel == 0) { v0*=0.125f; v1*=0.125f; v2*=0.125f; v3*=0.125f; }
        }
        size_t base = (size_t)pix*DM + head*EH;
        outp[base +  0 + col] = (_Float16)v0;
        outp[base + 16 + col] = (_Float16)v1;
        outp[base + 32 + col] = (_Float16)v2;
        outp[base + 48 + col] = (_Float16)v3;
    }
}

// ---------------- MFMA neighborhood attention (unchanged, validated) ----------------
__global__ __launch_bounds__(256) void attn_mfma(const _Float16* __restrict__ qg,
                                                 const _Float16* __restrict__ kg,
                                                 const _Float16* __restrict__ vg,
                                                 _Float16* __restrict__ obuf) {
    __shared__ _Float16 VT[64*232];   // [d][nb]
    __shared__ _Float16 SP[64*232];   // [q][nb]
    int t = threadIdx.x;
    int wave = t >> 6, lane = t & 63;
    int col = lane & 15, quad = lane >> 4;
    int ty = blockIdx.x / 6, tx = blockIdx.x % 6;
    int b = blockIdx.y >> 2, head = blockIdx.y & 3;
    int qh0 = ty*8, qw0 = tx*8;
    int rh0 = min(max(qh0-3, 0), HH-14);
    int rw0 = min(max(qw0-3, 0), WW-14);

    {
        int nbl = t & 31;
        int e0  = (t >> 5) * 8;
        #pragma unroll
        for (int pass = 0; pass < 7; ++pass) {
            int nb = pass*32 + nbl;
            int nr = nb >> 4, nc = nb & 15;
            int pix = (b*HH + rh0+nr)*WW + rw0 + nc;
            half8 vv = *(const half8*)(vg + (size_t)pix*DM + head*EH + e0);
            #pragma unroll
            for (int i = 0; i < 8; ++i)
                VT[(e0+i)*232 + nb] = vv[i];
        }
    }

    int qidx_a = wave*16 + col;
    int pixq = (b*HH + qh0 + (qidx_a>>3))*WW + qw0 + (qidx_a & 7);
    const _Float16* qp = qg + (size_t)pixq*DM + head*EH;
    half8 qf0 = *(const half8*)(qp + quad*8);
    half8 qf1 = *(const half8*)(qp + 32 + quad*8);

    float4v s[14];
    #pragma unroll
    for (int nr = 0; nr < 14; ++nr) {
        int pixk = (b*HH + rh0+nr)*WW + rw0 + col;
        const _Float16* kp = kg + (size_t)pixk*DM + head*EH;
        half8 kf0 = *(const half8*)(kp + quad*8);
        half8 kf1 = *(const half8*)(kp + 32 + quad*8);
        float4v a = (float4v){0.f,0.f,0.f,0.f};
        a = __builtin_amdgcn_mfma_f32_16x16x32_f16(qf0, kf0, a, 0, 0, 0);
        a = __builtin_amdgcn_mfma_f32_16x16x32_f16(qf1, kf1, a, 0, 0, 0);
        s[nr] = a;
    }

    int sh_[4], uw_[4];
    #pragma unroll
    for (int r = 0; r < 4; ++r) {
        int qidx = wave*16 + quad*4 + r;
        int qhh = qh0 + (qidx>>3), qww = qw0 + (qidx & 7);
        sh_[r] = min(max(qhh-3, 0), HH-KS);
        int sw_ = min(max(qww-3, 0), WW-KS);
        uw_[r] = rw0 + col - sw_;
    }
    #pragma unroll
    for (int nr = 0; nr < 14; ++nr)
        #pragma unroll
        for (int r = 0; r < 4; ++r) {
            int uh = rh0 + nr - sh_[r];
            bool ok = ((unsigned)uh < 7u) && ((unsigned)uw_[r] < 7u);
            s[nr][r] = ok ? s[nr][r] : -1e30f;
        }
    #pragma unroll
    for (int r = 0; r < 4; ++r) {
        float m = s[0][r];
        #pragma unroll
        for (int nr = 1; nr < 14; ++nr) m = fmaxf(m, s[nr][r]);
        m = fmaxf(m, __shfl_xor(m, 1, 64));
        m = fmaxf(m, __shfl_xor(m, 2, 64));
        m = fmaxf(m, __shfl_xor(m, 4, 64));
        m = fmaxf(m, __shfl_xor(m, 8, 64));
        float sum = 0.f;
        #pragma unroll
        for (int nr = 0; nr < 14; ++nr) { float p = __expf(s[nr][r] - m); s[nr][r] = p; sum += p; }
        sum += __shfl_xor(sum, 1, 64);
        sum += __shfl_xor(sum, 2, 64);
        sum += __shfl_xor(sum, 4, 64);
        sum += __shfl_xor(sum, 8, 64);
        float rs = 1.f / sum;
        #pragma unroll
        for (int nr = 0; nr < 14; ++nr)
            SP[(wave*16 + quad*4 + r)*232 + nr*16 + col] = (_Float16)(s[nr][r] * rs);
    }
    __syncthreads();

    float4v o[4];
    #pragma unroll
    for (int dt = 0; dt < 4; ++dt) o[dt] = (float4v){0.f,0.f,0.f,0.f};
    #pragma unroll
    for (int ks = 0; ks < 7; ++ks) {
        half8 pa = *(const half8*)&SP[(wave*16 + col)*232 + ks*32 + quad*8];
        #pragma unroll
        for (int dt = 0; dt < 4; ++dt) {
            half8 vf = *(const half8*)&VT[(dt*16 + col)*232 + ks*32 + quad*8];
            o[dt] = __builtin_amdgcn_mfma_f32_16x16x32_f16(pa, vf, o[dt], 0, 0, 0);
        }
    }
    #pragma unroll
    for (int r = 0; r < 4; ++r) {
        int qidx = wave*16 + quad*4 + r;
        int pix = (b*HH + qh0 + (qidx>>3))*WW + qw0 + (qidx & 7);
        #pragma unroll
        for (int dt = 0; dt < 4; ++dt)
            obuf[(size_t)pix*DM + head*EH + dt*16 + col] = (_Float16)o[dt][r];
    }
}

// ---------------- out GEMM: C = obuf @ w_out^T + skip ----------------
// 32x64 tile (576 blocks, 2.25/CU), whole-K LDS staging, barrier-free k-loop.
__global__ __launch_bounds__(256) void gemm_out_f16(const _Float16* __restrict__ A,
                                                    const float* __restrict__ B,
                                                    float* __restrict__ C,
                                                    const float* __restrict__ skip) {
    const int K = DM, N = DM, LDA = 264;
    __shared__ _Float16 As[32*LDA];
    __shared__ _Float16 Bs[64*LDA];
    int t = threadIdx.x;
    int wave = t >> 6, lane = t & 63;
    int m0 = blockIdx.x*32, n0 = blockIdx.y*64;

    // stage A (fp16): thread (row=t>>3, seg=t&7) owns 32 halves
    {
        int row = t >> 3, seg = t & 7;
        const _Float16* ap = A + (size_t)(m0+row)*K + seg*32;
        #pragma unroll
        for (int j = 0; j < 4; ++j)
            *(half8*)&As[row*LDA + seg*32 + j*8] = *(const half8*)(ap + j*8);
    }
    // stage B (fp32 -> fp16): thread (row=t>>2, seg=t&3) owns 64 floats
    {
        int row = t >> 2, seg = t & 3;
        const float4* bp = (const float4*)(B + (size_t)(n0+row)*K + seg*64);
        #pragma unroll
        for (int j = 0; j < 8; ++j) {
            float4 b0 = bp[2*j], b1 = bp[2*j+1];
            half8 hb;
            hb[0]=(_Float16)b0.x; hb[1]=(_Float16)b0.y; hb[2]=(_Float16)b0.z; hb[3]=(_Float16)b0.w;
            hb[4]=(_Float16)b1.x; hb[5]=(_Float16)b1.y; hb[6]=(_Float16)b1.z; hb[7]=(_Float16)b1.w;
            *(half8*)&Bs[row*LDA + seg*64 + j*8] = hb;
        }
    }
    __syncthreads();

    int frow = lane & 15, kq = (lane >> 4) * 8;
    int mrow  = (wave & 1) * 16;    // wave covers (mrow, nbase) quadrant
    int nbase = (wave >> 1) * 32;
    float4v acc[2];
    acc[0] = (float4v){0.f,0.f,0.f,0.f};
    acc[1] = (float4v){0.f,0.f,0.f,0.f};
    #pragma unroll
    for (int ks = 0; ks < 8; ++ks) {
        int k0 = ks*32;
        half8 af = *(const half8*)&As[(mrow + frow)*LDA + k0 + kq];
        #pragma unroll
        for (int ni = 0; ni < 2; ++ni) {
            half8 bf = *(const half8*)&Bs[(nbase + ni*16 + frow)*LDA + k0 + kq];
            acc[ni] = __builtin_amdgcn_mfma_f32_16x16x32_f16(af, bf, acc[ni], 0, 0, 0);
        }
    }

    int col = lane & 15, rbase = (lane >> 4) * 4;
    #pragma unroll
    for (int ni = 0; ni < 2; ++ni) {
        #pragma unroll
        for (int r = 0; r < 4; ++r) {
            int rowg = m0 + mrow + rbase + r;
            int c    = n0 + nbase + ni*16 + col;
            C[(size_t)rowg*N + c] = acc[ni][r] + skip[(size_t)rowg*N + c];
        }
    }
}

extern "C" void kernel_launch(void* const* d_in, const int* in_sizes, int n_in,
                              void* d_out, int out_size, void* d_ws, size_t ws_size,
                              hipStream_t stream) {
    const float* x      = (const float*)d_in[0];
    const float* pos    = (const float*)d_in[1];
    const float* cond   = (const float*)d_in[2];
    const float* w_norm = (const float*)d_in[3];
    const float* w_qkv  = (const float*)d_in[4];
    const float* w_out  = (const float*)d_in[5];
    float* out = (float*)d_out;
    char* base = (char*)d_ws;

    const size_t SZH = (size_t)NPIX*DM*2;   // fp16 [pix][256]: 2,359,296 B
    const size_t PAD = 4096;                // attn edge reads overrun <=2 pixels
    float*    scale  = (float*)(base);
    _Float16* qh     = (_Float16*)(base + PAD + 0*(SZH+PAD));
    _Float16* kh     = (_Float16*)(base + PAD + 1*(SZH+PAD));
    _Float16* vh     = (_Float16*)(base + PAD + 2*(SZH+PAD));
    _Float16* obuf_h = (_Float16*)(base + PAD + 3*(SZH+PAD));

    scale_kernel<<<dim3(N_B, 8), 256, 0, stream>>>(cond, w_norm, scale);
    fused_qkv<<<dim3(NPIX/64, 12), 256, 0, stream>>>(x, scale, w_qkv, pos, qh, kh, vh);
    attn_mfma<<<dim3(36, N_B*NH), 256, 0, stream>>>(qh, kh, vh, obuf_h);
    gemm_out_f16<<<dim3(NPIX/32, DM/64), 256, 0, stream>>>(obuf_h, w_out, out, x);
}